// Round 6
// baseline (691.547 us; speedup 1.0000x reference)
//
#include <hip/hip_runtime.h>
#include <cstdint>

typedef unsigned short u16;
typedef __bf16 bf16x8 __attribute__((ext_vector_type(8)));
typedef float f32x4 __attribute__((ext_vector_type(4)));
typedef _Float16 f16x8 __attribute__((ext_vector_type(8)));

#define LN_EPS 1e-5f

__device__ __forceinline__ u16 f2b(float f) {
    union { float f; unsigned int i; } v;
    v.f = f;
    unsigned int u = v.i;
    unsigned int r = (u + 0x7FFFu + ((u >> 16) & 1u)) >> 16;  // RNE
    return (u16)r;
}

// ---------------------------------------------------------------------------
// prep_weights v2 (unchanged, verified): WT in MFMA-fragment-packed layout.
//   group g = kp*64 + cg (kp=k/32, cg=col/16); within group, lane q*16+r16
//   holds col cg*16+r16, k = kp*32+q*8+j at elem (g*64+lane)*8+j.
// A wave's B-frag load is one contiguous 1KB burst.
// ---------------------------------------------------------------------------
__global__ __launch_bounds__(256) void prep_weights(
    const float* __restrict__ W, const float* __restrict__ adj,
    u16* __restrict__ WTp, int F)
{
    __shared__ float tile[64][65];
    const int tid = threadIdx.x;
    const size_t lofs = (size_t)blockIdx.z * F * F;
    const int kb = blockIdx.y * 64;
    const int fb = blockIdx.x * 64;
    const int c  = tid & 63;
    const int r0t = tid >> 6;

#pragma unroll
    for (int i = 0; i < 16; ++i) {
        int kl = r0t + i * 4;
        int k = kb + kl, f = fb + c;
        tile[kl][c] = W[lofs + (size_t)k * F + f] * adj[(size_t)k * F + f];
    }
    __syncthreads();

#pragma unroll
    for (int c2 = 0; c2 < 2; ++c2) {
        const int cid   = c2 * 256 + tid;      // 0..511 16B-chunks
        const int lane_ = cid & 63;
        const int cgl   = (cid >> 6) & 3;      // local colgroup 0..3
        const int kp2   = cid >> 8;            // local kp 0..1
        const int fl    = cgl * 16 + (lane_ & 15);
        const int klb   = kp2 * 32 + (lane_ >> 4) * 8;
        const size_t g  = (size_t)((kb >> 5) + kp2) * 64 + (fb >> 4) + cgl;
        u16* dst = WTp + lofs + (g * 64 + lane_) * 8;
        ushort4 lo, hi;
        lo.x = f2b(tile[klb + 0][fl]); lo.y = f2b(tile[klb + 1][fl]);
        lo.z = f2b(tile[klb + 2][fl]); lo.w = f2b(tile[klb + 3][fl]);
        hi.x = f2b(tile[klb + 4][fl]); hi.y = f2b(tile[klb + 5][fl]);
        hi.z = f2b(tile[klb + 6][fl]); hi.w = f2b(tile[klb + 7][fl]);
        ((ushort4*)dst)[0] = lo;
        ((ushort4*)dst)[1] = hi;
    }
}

// ---------------------------------------------------------------------------
// chain v6: 64 rows/block, 1024 threads (16 waves = 2 row-halves x 8 col
// slices), 1 block/CU, 4 waves/SIMD. Halves B traffic vs R5 (256 blocks x
// 2MB x 5 = 2.6GB at L2/L3); the wr=0/1 wave pair reads identical B bursts
// close in time -> L1 dedup. Per-thread workload identical to verified R5
// (acc[2][8] = 64 AGPR, rolling b0/b1 prefetch, ~128 regs, barrier-free
// K-loop). ALL nontemporal hints dropped: R5's nt Hf stores write-amplified
// 134->~536MB at HBM and forced HBM-latency readbacks; plain accesses let
// the 256MB L3 absorb the whole 33.6MB residual round-trip.
// ---------------------------------------------------------------------------
__global__ __launch_bounds__(1024, 4) void chain(
    const float* __restrict__ X,     // (N,F) fp32 input
    const u16* __restrict__ WT,      // (L, 4096 groups, 64 lanes, 8) packed
    const float* __restrict__ Bias,  // (L,F) fp32
    _Float16* __restrict__ Hf,       // fp16 residual ws, wave-contiguous
    float* __restrict__ Out,         // (N,F) fp32 output
    int N, int L)
{
    constexpr int F = 1024;
    constexpr int K = 1024;
    constexpr int ROWS = 64;
    extern __shared__ char smem[];
    // [0,131072): A tile [64][1024] bf16, swizzled
    float* wsS = (float*)(smem + 131072);  // [16][32]
    float* wsQ = (float*)(smem + 133120);  // [16][32]
    float* mr  = (float*)(smem + 135168);  // [64][2] mean,rstd

    const int tid  = threadIdx.x;
    const int wv   = tid >> 6;        // wave 0..15
    const int wc   = wv >> 1;         // col slice 0..7 -> cols [128wc,..)
    const int wr   = wv & 1;          // row half 0..1 -> rows [32wr,..)
    const int lane = tid & 63;
    const int q    = lane >> 4;       // 0..3
    const int r16  = lane & 15;
    const int s3   = r16 & 7;         // A-swizzle key
    const int r0   = blockIdx.x * ROWS;

    const size_t ff = (size_t)F * K;

    // ---- stage A from X (fp32 -> bf16, swizzled), coalesced float4 ----
    {
        const float4* Xv = (const float4*)(X + (size_t)r0 * F);
#pragma unroll 4
        for (int i = 0; i < 16; ++i) {
            int e4 = i * 1024 + tid;           // 0..16383
            float4 v = Xv[e4];
            int el  = e4 * 4;
            int row = el >> 10;                // 0..63
            int col = el & 1023;
            int chunk = (col >> 3) ^ (row & 7);
            int boff  = row * 2048 + chunk * 16 + (col & 7) * 2;
            ushort4 pk;
            pk.x = f2b(v.x); pk.y = f2b(v.y); pk.z = f2b(v.z); pk.w = f2b(v.w);
            *(ushort4*)(smem + boff) = pk;
        }
    }
    __syncthreads();

    const int aB0 = (wr * 32 + r16) * 2048;        // rows wr*32 + 0..15
    const int aB1 = (wr * 32 + 16 + r16) * 2048;   // rows wr*32 + 16..31

    // packed-B: this wave's first group = wc*8; lane's 16B chunk.
    const unsigned bBase = (unsigned)((wc * 8) * 64 + lane) * 8;
    // kp stride = 64 groups * 64 lanes * 8 = 32768 elems

    // Hf: [block][wave][8 j][64 lanes][8 elems] -> 1KB bursts per store
    const size_t hb = (size_t)blockIdx.x * 65536 + (size_t)wv * 4096
                    + (size_t)lane * 8;

    for (int l = 0; l < L; ++l) {
        const u16* wt = WT + (size_t)l * ff;

        f32x4 acc[2][8];
        const f32x4 zero = {0.f, 0.f, 0.f, 0.f};
#pragma unroll
        for (int mi = 0; mi < 2; ++mi)
#pragma unroll
            for (int ni = 0; ni < 8; ++ni) acc[mi][ni] = zero;

        bf16x8 b0[4], b1[4];
        {
            const u16* p0 = wt + bBase;
#pragma unroll
            for (int i = 0; i < 4; ++i)
                b0[i] = *(const bf16x8*)(p0 + i * 512);
#pragma unroll
            for (int i = 0; i < 4; ++i)
                b1[i] = *(const bf16x8*)(p0 + 2048 + i * 512);
        }

        for (int kp = 0; kp < 32; ++kp) {
            const int kc = kp * 4 + q;
            const bf16x8 af0 = *(const bf16x8*)(smem + aB0 + ((kc ^ s3) << 4));
            const bf16x8 af1 = *(const bf16x8*)(smem + aB1 + ((kc ^ s3) << 4));
            const u16* nxt = wt + (((kp + 1) & 31) << 15) + bBase;

            __builtin_amdgcn_s_setprio(1);
#pragma unroll
            for (int i = 0; i < 4; ++i) {
                acc[0][i] = __builtin_amdgcn_mfma_f32_16x16x32_bf16(
                    af0, b0[i], acc[0][i], 0, 0, 0);
                acc[1][i] = __builtin_amdgcn_mfma_f32_16x16x32_bf16(
                    af1, b0[i], acc[1][i], 0, 0, 0);
            }
            __builtin_amdgcn_s_setprio(0);
#pragma unroll
            for (int i = 0; i < 4; ++i)          // reload right after last use
                b0[i] = *(const bf16x8*)(nxt + i * 512);

            __builtin_amdgcn_s_setprio(1);
#pragma unroll
            for (int i = 0; i < 4; ++i) {
                acc[0][4 + i] = __builtin_amdgcn_mfma_f32_16x16x32_bf16(
                    af0, b1[i], acc[0][4 + i], 0, 0, 0);
                acc[1][4 + i] = __builtin_amdgcn_mfma_f32_16x16x32_bf16(
                    af1, b1[i], acc[1][4 + i], 0, 0, 0);
            }
            __builtin_amdgcn_s_setprio(0);
#pragma unroll
            for (int i = 0; i < 4; ++i)
                b1[i] = *(const bf16x8*)(nxt + 2048 + i * 512);
        }

        // ---- epilogue: bias + relu + residual (fp32 math) ----
        // col(ni) = wc*128 + ni*16 + r16 ; row = wr*32 + mi*16 + q*4 + j
        float bv[8];
#pragma unroll
        for (int ni = 0; ni < 8; ++ni)
            bv[ni] = Bias[(size_t)l * F + wc * 128 + ni * 16 + r16];

        if (l == 0) {
#pragma unroll
            for (int mi = 0; mi < 2; ++mi) {
                const int rl = wr * 32 + mi * 16 + q * 4;
#pragma unroll
                for (int ni = 0; ni < 8; ++ni) {
                    const int cl = wc * 128 + ni * 16 + r16;
                    const size_t g = (size_t)(r0 + rl) * F + cl;
#pragma unroll
                    for (int j = 0; j < 4; ++j) {
                        float h = X[g + (size_t)j * F];
                        acc[mi][ni][j] = fmaxf(acc[mi][ni][j] + bv[ni], 0.f) + h;
                    }
                }
            }
        } else {
#pragma unroll
            for (int j = 0; j < 8; ++j) {
                f16x8 v = *(const f16x8*)(Hf + hb + j * 512);
#pragma unroll
                for (int half = 0; half < 2; ++half) {
                    const int c  = j * 2 + half;
                    const int mi = c >> 3, ni = c & 7;
#pragma unroll
                    for (int jj = 0; jj < 4; ++jj) {
                        float h = (float)v[half * 4 + jj];
                        acc[mi][ni][jj] =
                            fmaxf(acc[mi][ni][jj] + bv[ni], 0.f) + h;
                    }
                }
            }
        }

        // ---- LN stats: in-lane over ni, 16-lane butterfly, LDS x-wave ----
        float sS[2][4], sQ[2][4];
#pragma unroll
        for (int mi = 0; mi < 2; ++mi)
#pragma unroll
            for (int j = 0; j < 4; ++j) {
                float s = 0.f, s2 = 0.f;
#pragma unroll
                for (int ni = 0; ni < 8; ++ni) {
                    float y = acc[mi][ni][j];
                    s += y; s2 = fmaf(y, y, s2);
                }
#pragma unroll
                for (int m = 1; m < 16; m <<= 1) {
                    s  += __shfl_xor(s,  m, 64);
                    s2 += __shfl_xor(s2, m, 64);
                }
                sS[mi][j] = s; sQ[mi][j] = s2;
            }

        if (r16 == 0) {
#pragma unroll
            for (int mi = 0; mi < 2; ++mi)
#pragma unroll
                for (int j = 0; j < 4; ++j) {
                    int row32 = mi * 16 + q * 4 + j;      // 0..31
                    wsS[wv * 32 + row32] = sS[mi][j];
                    wsQ[wv * 32 + row32] = sQ[mi][j];
                }
        }
        __syncthreads();   // also: all waves done reading A this layer
        if (tid < 64) {
            const int wrr = tid >> 5, rl = tid & 31;
            float s = 0.f, s2 = 0.f;
#pragma unroll
            for (int c8 = 0; c8 < 8; ++c8) {
                s  += wsS[(c8 * 2 + wrr) * 32 + rl];
                s2 += wsQ[(c8 * 2 + wrr) * 32 + rl];
            }
            float mean = s * (1.f / 1024.f);
            float var  = s2 * (1.f / 1024.f) - mean * mean;
            mr[tid * 2]     = mean;
            mr[tid * 2 + 1] = rsqrtf(var + LN_EPS);
        }
        __syncthreads();

        float mean_[2][4], rstd_[2][4];
#pragma unroll
        for (int mi = 0; mi < 2; ++mi)
#pragma unroll
            for (int j = 0; j < 4; ++j) {
                int row = wr * 32 + mi * 16 + q * 4 + j;
                mean_[mi][j] = mr[row * 2];
                rstd_[mi][j] = mr[row * 2 + 1];
            }

        // ---- normalize; write next-h (A LDS + Hf) or final Out ----
        if (l == L - 1) {
#pragma unroll
            for (int mi = 0; mi < 2; ++mi)
#pragma unroll
                for (int ni = 0; ni < 8; ++ni) {
                    const int cl = wc * 128 + ni * 16 + r16;
#pragma unroll
                    for (int j = 0; j < 4; ++j) {
                        const int row = wr * 32 + mi * 16 + q * 4 + j;
                        float yn = (acc[mi][ni][j] - mean_[mi][j]) * rstd_[mi][j];
                        Out[(size_t)(r0 + row) * F + cl] = yn;
                    }
                }
        } else {
            _Float16 hbuf[64];
#pragma unroll
            for (int mi = 0; mi < 2; ++mi)
#pragma unroll
                for (int ni = 0; ni < 8; ++ni) {
                    const int cl = wc * 128 + ni * 16 + r16;
#pragma unroll
                    for (int j = 0; j < 4; ++j) {
                        const int row = wr * 32 + mi * 16 + q * 4 + j;
                        float yn = (acc[mi][ni][j] - mean_[mi][j]) * rstd_[mi][j];
                        hbuf[(mi * 8 + ni) * 4 + j] = (_Float16)yn;
                        int chunk = (cl >> 3) ^ (row & 7);
                        int boff  = row * 2048 + chunk * 16 + (cl & 7) * 2;
                        *(u16*)(smem + boff) = f2b(yn);
                    }
                }
#pragma unroll
            for (int j = 0; j < 8; ++j)
                *(f16x8*)(Hf + hb + j * 512) = *(const f16x8*)(hbuf + j * 8);
        }
        __syncthreads();   // A rewritten + mr consumed before next layer
    }
}

// ---------------------------------------------------------------------------
extern "C" void kernel_launch(void* const* d_in, const int* in_sizes, int n_in,
                              void* d_out, int out_size, void* d_ws, size_t ws_size,
                              hipStream_t stream) {
    const float* x    = (const float*)d_in[0];   // fp32 (N,F)
    const float* adj  = (const float*)d_in[1];   // fp32 (F,F)
    const float* W    = (const float*)d_in[2];   // fp32 (L,F,F)
    const float* bias = (const float*)d_in[3];   // fp32 (L,F)
    float* out = (float*)d_out;                  // fp32 (N,F)

    const int L = in_sizes[2] / in_sizes[1];     // 5
    const int F = in_sizes[3] / L;               // 1024
    const int N = in_sizes[0] / F;               // 16384

    const size_t ff = (size_t)F * F;

    // ws: WT packed (L*ff bf16, 10.5 MB) + Hf fp16 residual (33.6 MB)
    u16* WT = (u16*)d_ws;
    _Float16* Hf = (_Float16*)((char*)d_ws + (size_t)L * ff * sizeof(u16));

    prep_weights<<<dim3(F / 64, F / 64, L), 256, 0, stream>>>(W, adj, WT, F);

    constexpr unsigned SMEM = 135680;  // 128KB A + 4KB stats + 512B mean/rstd
    static bool attrSet = false;
    if (!attrSet) {
        (void)hipFuncSetAttribute(reinterpret_cast<const void*>(chain),
                                  hipFuncAttributeMaxDynamicSharedMemorySize,
                                  (int)SMEM);
        attrSet = true;
    }
    chain<<<N / 64, 1024, SMEM, stream>>>(x, WT, bias, Hf, out, N, L);
}